// Round 19
// baseline (223.758 us; speedup 1.0000x reference)
//
#include <hip/hip_runtime.h>
#include <math.h>

#define Bc  32
#define Hc  8
#define LQc 256
#define LVc 1024
#define Dc  512

// per-wave drain of outstanding global_load_lds BEFORE a barrier publishes
// the staged LDS to other waves (vmcnt is per-wave; R10/R12-proven).
#define VMCNT0 asm volatile("s_waitcnt vmcnt(0)" ::: "memory")

typedef short bf16x8 __attribute__((ext_vector_type(8)));
typedef float f32x4  __attribute__((ext_vector_type(4)));

__device__ __forceinline__ unsigned short f2bf(float x) {   // RNE fp32->bf16
    unsigned u = __builtin_bit_cast(unsigned, x);
    u = (u + 0x7fffu + ((u >> 16) & 1u)) >> 16;
    return (unsigned short)u;
}

__device__ __forceinline__ bf16x8 pack8(float4 a, float4 b) {
    bf16x8 r;
    r[0] = (short)f2bf(a.x); r[1] = (short)f2bf(a.y);
    r[2] = (short)f2bf(a.z); r[3] = (short)f2bf(a.w);
    r[4] = (short)f2bf(b.x); r[5] = (short)f2bf(b.y);
    r[6] = (short)f2bf(b.z); r[7] = (short)f2bf(b.w);
    return r;
}

__device__ __forceinline__ void gload16(const ushort* g, ushort* l) {
    __builtin_amdgcn_global_load_lds(
        (const __attribute__((address_space(1))) unsigned*)g,
        (__attribute__((address_space(3))) unsigned*)l, 16, 0, 0);
}

// ---------------------------------------------------------------------------
// All weight prep in ONE launch. grid (16,16,5), 256 thr.
// ---------------------------------------------------------------------------
__global__ __launch_bounds__(256) void prep_w(const float* __restrict__ Wq,
                                              const float* __restrict__ Wk,
                                              const float* __restrict__ Wv,
                                              const float* __restrict__ Wo,
                                              const float* __restrict__ Wl,
                                              ushort* __restrict__ wqT,
                                              ushort* __restrict__ wkT,
                                              ushort* __restrict__ wvT,
                                              ushort* __restrict__ woBf,
                                              ushort* __restrict__ wlBf) {
    const int z = blockIdx.z;
    if (z < 3) {
        __shared__ float t[32][33];
        const float* in = (z == 0) ? Wq : (z == 1) ? Wk : Wv;
        ushort* out = (z == 0) ? wqT : (z == 1) ? wkT : wvT;
        const int l0 = blockIdx.x * 32, d0 = blockIdx.y * 32;
        const int r = threadIdx.x >> 5, c = threadIdx.x & 31;
#pragma unroll
        for (int i = 0; i < 4; i++)
            t[r + 8 * i][c] = in[(size_t)(l0 + r + 8 * i) * 512 + d0 + c];
        __syncthreads();
#pragma unroll
        for (int i = 0; i < 4; i++)
            out[(size_t)(d0 + r + 8 * i) * 512 + l0 + c] = f2bf(t[c][r + 8 * i]);
    } else {
        const float* in = (z == 3) ? Wo : Wl;
        ushort* out = (z == 3) ? woBf : wlBf;
        const int i = (blockIdx.y * 16 + blockIdx.x) * 256 + threadIdx.x;
        float4 v = ((const float4*)in)[i];
        ushort4 o;
        o.x = f2bf(v.x); o.y = f2bf(v.y); o.z = f2bf(v.z); o.w = f2bf(v.w);
        ((ushort4*)out)[i] = o;
    }
}

// ---------------------------------------------------------------------------
// FUSED length-projection from raw fp32 keys/values (transpose in-LDS).
// t1[z][q][d] = b_len[q] + sum_l Wl[q][l] * X[z][l][d]    (bf16 out)
// ---------------------------------------------------------------------------
__global__ __launch_bounds__(256) void lenproj_f32(const ushort* __restrict__ wl,
                                                   const float* __restrict__ keys,
                                                   const float* __restrict__ vals,
                                                   const float* __restrict__ bias,
                                                   ushort* __restrict__ t1k) {
    __shared__ __align__(16) ushort Wls[4096];       // chunked A tile, 8 KB
    __shared__ __align__(16) float  Xsf[128 * 36];   // transposed X tile, 18 KB

    const int z = blockIdx.z;
    const float* X = ((z < 32) ? keys : vals) + (size_t)(z & 31) * LVc * Dc;
    ushort* C = t1k + (size_t)z * LQc * Dc;

    const int bm = blockIdx.y * 128;     // q
    const int bn = blockIdx.x * 128;     // d
    const int tid = threadIdx.x;
    const int wave = tid >> 6, l = tid & 63;
    const int wm = (wave >> 1) * 64, wn = (wave & 1) * 64;
    const int l15 = l & 15, lh = l >> 4;

    f32x4 acc[4][4];
#pragma unroll
    for (int m = 0; m < 4; m++)
#pragma unroll
        for (int n = 0; n < 4; n++) acc[m][n] = (f32x4){0.f, 0.f, 0.f, 0.f};

    const int lrow = tid >> 3;               // 0..31 (l within tile)
    const int dcol = (tid & 7) * 16;         // 0..112 (d within tile)

    for (int l0 = 0; l0 < LVc; l0 += 32) {
        gload16(wl + (size_t)(bm + wave * 16 + l15) * LVc + l0 + lh * 8,
                Wls + wave * 512);
        gload16(wl + (size_t)(bm + 64 + wave * 16 + l15) * LVc + l0 + lh * 8,
                Wls + (wave + 4) * 512);
        const float* xs = X + (size_t)(l0 + lrow) * Dc + bn + dcol;
        float4 xv0 = ((const float4*)xs)[0];
        float4 xv1 = ((const float4*)xs)[1];
        float4 xv2 = ((const float4*)xs)[2];
        float4 xv3 = ((const float4*)xs)[3];
        Xsf[(dcol + 0)  * 36 + lrow] = xv0.x;
        Xsf[(dcol + 1)  * 36 + lrow] = xv0.y;
        Xsf[(dcol + 2)  * 36 + lrow] = xv0.z;
        Xsf[(dcol + 3)  * 36 + lrow] = xv0.w;
        Xsf[(dcol + 4)  * 36 + lrow] = xv1.x;
        Xsf[(dcol + 5)  * 36 + lrow] = xv1.y;
        Xsf[(dcol + 6)  * 36 + lrow] = xv1.z;
        Xsf[(dcol + 7)  * 36 + lrow] = xv1.w;
        Xsf[(dcol + 8)  * 36 + lrow] = xv2.x;
        Xsf[(dcol + 9)  * 36 + lrow] = xv2.y;
        Xsf[(dcol + 10) * 36 + lrow] = xv2.z;
        Xsf[(dcol + 11) * 36 + lrow] = xv2.w;
        Xsf[(dcol + 12) * 36 + lrow] = xv3.x;
        Xsf[(dcol + 13) * 36 + lrow] = xv3.y;
        Xsf[(dcol + 14) * 36 + lrow] = xv3.z;
        Xsf[(dcol + 15) * 36 + lrow] = xv3.w;
        VMCNT0;
        __syncthreads();

        bf16x8 af[4], bfr[4];
#pragma unroll
        for (int m = 0; m < 4; m++)
            af[m] = *(const bf16x8*)&Wls[((wm >> 4) + m) * 512 + lh * 128 + l15 * 8];
#pragma unroll
        for (int n = 0; n < 4; n++) {
            const float* fb = &Xsf[(wn + n * 16 + l15) * 36 + lh * 8];
            float4 x0 = *(const float4*)fb;
            float4 x1 = *(const float4*)(fb + 4);
            bfr[n] = pack8(x0, x1);
        }
#pragma unroll
        for (int m = 0; m < 4; m++)
#pragma unroll
            for (int n = 0; n < 4; n++)
                acc[m][n] = __builtin_amdgcn_mfma_f32_16x16x32_bf16(
                    af[m], bfr[n], acc[m][n], 0, 0, 0);
        __syncthreads();
    }

#pragma unroll
    for (int m = 0; m < 4; m++)
#pragma unroll
        for (int r = 0; r < 4; r++) {
            const int row = bm + wm + m * 16 + lh * 4 + r;
            const float bv = bias[row];
#pragma unroll
            for (int n = 0; n < 4; n++) {
                const int col = bn + wn + n * 16 + l15;
                C[(size_t)row * Dc + col] = f2bf(acc[m][n][r] + bv);
            }
        }
}

// ---------------------------------------------------------------------------
// C[m,n] = alpha * sum_k A[m,k]*B[n,k] (+ bias)         (bf16 in, f32 accum)
// ---------------------------------------------------------------------------
template <int STORE, bool BIAS, int SWIZ>
__global__ __launch_bounds__(256) void gemm_bt(const ushort* __restrict__ A,
                                               const ushort* __restrict__ B,
                                               void* __restrict__ Cv,
                                               const float* __restrict__ bias,
                                               int M, int N, int K, float alpha,
                                               long sA, long sB, long sC,
                                               int byPerXcd) {
    __shared__ ushort As[128 * 32];
    __shared__ ushort Bs[128 * 32];
    const int z = blockIdx.z;
    A += (size_t)z * sA;
    B += (size_t)z * sB;
    float*  Cf = (float*)Cv  + (size_t)z * sC;
    ushort* Ch = (ushort*)Cv + (size_t)z * sC;

    int bm, bn;
    if constexpr (SWIZ) {
        const int bid = blockIdx.x;
        const int xcd = bid & 7, slot = bid >> 3;
        bm = (xcd * byPerXcd + (slot >> 2)) * 128;
        bn = (slot & 3) * 128;
    } else {
        bm = blockIdx.y * 128;
        bn = blockIdx.x * 128;
    }
    const int tid = threadIdx.x;
    const int wave = tid >> 6, l = tid & 63;
    const int wm = (wave >> 1) * 64, wn = (wave & 1) * 64;
    const int l15 = l & 15, lh = l >> 4;

    f32x4 acc[4][4];
#pragma unroll
    for (int m = 0; m < 4; m++)
#pragma unroll
        for (int n = 0; n < 4; n++) acc[m][n] = (f32x4){0.f, 0.f, 0.f, 0.f};

    const int srow = tid >> 2, scol = (tid & 3) * 8;
    ushort* ldsA = As + (wave * 16) * 32;
    ushort* ldsB = Bs + (wave * 16) * 32;
    const ushort* gA = A + (size_t)(bm + srow) * K + scol;
    const ushort* gB = B + (size_t)(bn + srow) * K + scol;

    for (int k0 = 0; k0 < K; k0 += 32) {
        gload16(gA + k0, ldsA);
        gload16(gA + k0 + (size_t)64 * K, ldsA + 64 * 32);
        gload16(gB + k0, ldsB);
        gload16(gB + k0 + (size_t)64 * K, ldsB + 64 * 32);
        VMCNT0;
        __syncthreads();
        bf16x8 af[4], bfr[4];
#pragma unroll
        for (int m = 0; m < 4; m++)
            af[m] = *(const bf16x8*)&As[(wm + m * 16 + l15) * 32 + lh * 8];
#pragma unroll
        for (int n = 0; n < 4; n++)
            bfr[n] = *(const bf16x8*)&Bs[(wn + n * 16 + l15) * 32 + lh * 8];
#pragma unroll
        for (int m = 0; m < 4; m++)
#pragma unroll
            for (int n = 0; n < 4; n++)
                acc[m][n] = __builtin_amdgcn_mfma_f32_16x16x32_bf16(
                    af[m], bfr[n], acc[m][n], 0, 0, 0);
        __syncthreads();
    }

    if constexpr (STORE == 2) {
#pragma unroll
        for (int m = 0; m < 4; m++) {
            const int row0 = bm + wm + m * 16 + lh * 4;
            const int bb = row0 >> 8, q = row0 & 255;
            float bv[4] = {0.f, 0.f, 0.f, 0.f};
            if constexpr (BIAS) {
#pragma unroll
                for (int r = 0; r < 4; r++) bv[r] = bias[q + r];
            }
#pragma unroll
            for (int n = 0; n < 4; n++) {
                const int col = bn + wn + n * 16 + l15;
                ushort4 o;
                o.x = f2bf(acc[m][n][0] * alpha + bv[0]);
                o.y = f2bf(acc[m][n][1] * alpha + bv[1]);
                o.z = f2bf(acc[m][n][2] * alpha + bv[2]);
                o.w = f2bf(acc[m][n][3] * alpha + bv[3]);
                *(ushort4*)&Ch[(size_t)bb * N * 256 + (size_t)col * 256 + q] = o;
            }
        }
    } else if constexpr (STORE == 1) {
#pragma unroll
        for (int m = 0; m < 4; m++)
#pragma unroll
            for (int r = 0; r < 4; r++) {
                const int row = bm + wm + m * 16 + lh * 4 + r;
                const float bv = BIAS ? bias[row & 255] : 0.f;
#pragma unroll
                for (int n = 0; n < 4; n++) {
                    const int col = bn + wn + n * 16 + l15;
                    Ch[(size_t)row * N + col] = f2bf(acc[m][n][r] * alpha + bv);
                }
            }
    } else {
#pragma unroll
        for (int m = 0; m < 4; m++)
#pragma unroll
            for (int r = 0; r < 4; r++) {
                const int row = bm + wm + m * 16 + lh * 4 + r;
                const float bv = BIAS ? bias[row & 255] : 0.f;
#pragma unroll
                for (int n = 0; n < 4; n++) {
                    const int col = bn + wn + n * 16 + l15;
                    Cf[(size_t)row * N + col] = acc[m][n][r] * alpha + bv;
                }
            }
    }
}

// ---------------------------------------------------------------------------
// Fused attention v11 = v8 sync pattern with 8-WAVE blocks (512 thr).
// Same grid 512, same 80KB LDS -> 2 blocks/CU = 16 waves/CU (2x v8's 8).
// Wave w owns score rows [16w,16w+16): sacc[16], 1 Q-frag, 2 K-DMAs/iter,
// 16 MFMAs/iter. Phase B: wave w owns d-cols [16w,16w+16) per 128-chunk:
// 1 V-DMA + 8 MFMAs per l-step. Sync: stage -> compute -> VMCNT0 -> barrier
// (R12/R15-proven). Arithmetic bit-identical to v8.
// ---------------------------------------------------------------------------
__global__ __launch_bounds__(512, 2) void attn_mfma(const float* __restrict__ qf,
                                                    const ushort* __restrict__ k2,
                                                    const ushort* __restrict__ v2T,
                                                    const int* __restrict__ vlen,
                                                    float* __restrict__ aout) {
    __shared__ __align__(16) ushort pool[40960];     // 80 KB
    ushort* Ps = pool;                                // chunked P, [0, 32768)

    const int bid = blockIdx.x;
    const int xcd = bid & 7, pos = bid >> 3;      // 64 blocks per XCD
    const int b = xcd * 4 + (pos >> 4);           // 4 batches per XCD
    const int inner = pos & 15;
    const int h = inner >> 1, qh = inner & 1;
    const int n = b * 8 + h;
    const int q0 = qh * 128;

    const int tid = threadIdx.x, wave = tid >> 6, l = tid & 63;
    const int l15 = l & 15, lh = l >> 4;
    const int vl = vlen[b];

    const float*  qbase = qf  + ((size_t)n * LQc + q0) * Dc;
    const ushort* kbase = k2  + (size_t)b * LQc * Dc;
    const ushort* vbase = v2T + (size_t)b * LQc * Dc;

    // ---- phase A: scores 128x256; K dbuf in LDS, Q direct to regs -------
    f32x4 sacc[16];
#pragma unroll
    for (int fn = 0; fn < 16; fn++) sacc[fn] = (f32x4){0.f, 0.f, 0.f, 0.f};

    auto STAGE_K = [&](int bi, int k0) {          // 2 DMAs per wave
        ushort* k_ = pool + bi * 8192;            // 16 KB per buffer
#pragma unroll
        for (int j = 0; j < 2; j++)
            gload16(kbase + (size_t)((wave * 2 + j) * 16 + l15) * Dc + k0 + lh * 8,
                    k_ + (wave * 2 + j) * 512);
    };

    STAGE_K(0, 0);
    VMCNT0;
    __syncthreads();
    for (int t = 0; t < 16; ++t) {
        const int k0 = t * 32;
        if (t < 15) STAGE_K((t + 1) & 1, k0 + 32);
        // Q fragment straight from global (read-once data), rows 16w+l15
        const float* fb = qbase + (size_t)(wave * 16 + l15) * Dc + k0 + lh * 8;
        float4 x0 = *(const float4*)fb;
        float4 x1 = *(const float4*)(fb + 4);
        bf16x8 aq = pack8(x0, x1);
        const ushort* k_ = pool + (t & 1) * 8192;
#pragma unroll
        for (int fn = 0; fn < 16; fn++) {
            bf16x8 bk = *(const bf16x8*)&k_[fn * 512 + lh * 128 + l15 * 8];
            sacc[fn] = __builtin_amdgcn_mfma_f32_16x16x32_bf16(aq, bk, sacc[fn], 0, 0, 0);
        }
        VMCNT0;            // drain STAGE_K(t+1) before publishing via barrier
        __syncthreads();
    }

    // ---- prefetch first V tile (hides under softmax VALU) ---------------
    auto STAGE_V = [&](int bi, int it) {          // 1 DMA per wave
        const int d0 = (it >> 3) * 128, l0 = (it & 7) * 32;
        ushort* v_ = pool + 32768 + bi * 4096;
        gload16(vbase + (size_t)(d0 + wave * 16 + l15) * LQc + l0 + lh * 8,
                v_ + wave * 512);
    };
    STAGE_V(0, 0);

    // ---- softmax: wave owns rows [16w,16w+16); normalize before write ---
#pragma unroll
    for (int r = 0; r < 4; r++) {
        const int rowl = wave * 16 + lh * 4 + r;
        float v[16];
        float rmax = -3.4e38f;
#pragma unroll
        for (int fn = 0; fn < 16; fn++) {
            const int col = fn * 16 + l15;
            float s = sacc[fn][r];
            v[fn] = (col < vl) ? s : -1e6f;
            rmax = fmaxf(rmax, v[fn]);
        }
        rmax = fmaxf(rmax, __shfl_xor(rmax, 1));
        rmax = fmaxf(rmax, __shfl_xor(rmax, 2));
        rmax = fmaxf(rmax, __shfl_xor(rmax, 4));
        rmax = fmaxf(rmax, __shfl_xor(rmax, 8));
        float rsum = 0.f;
#pragma unroll
        for (int fn = 0; fn < 16; fn++) {
            v[fn] = __expf(v[fn] - rmax);
            rsum += v[fn];
        }
        rsum += __shfl_xor(rsum, 1);
        rsum += __shfl_xor(rsum, 2);
        rsum += __shfl_xor(rsum, 4);
        rsum += __shfl_xor(rsum, 8);
        const float rinv = 1.0f / rsum;
        // chunked P write: row = wave*16+lh*4+r, col = fn*16+l15
        const int base = wave * 4096 + (lh * 4 + r) * 8 + (l15 & 7);
        const int chi = (l15 >> 3) * 128;
#pragma unroll
        for (int fn = 0; fn < 16; fn++)
            Ps[base + fn * 256 + chi] = f2bf(v[fn] * rinv);
    }
    VMCNT0;                // drain STAGE_V(0,0) before publishing
    __syncthreads();       // Ps visible + V tile 0 loaded

    // ---- phase B: out = P @ v2, 4 d-chunks of 128, 2-phase dbuf ---------
    int it = 0;
    for (int d0 = 0; d0 < Dc; d0 += 128) {
        f32x4 o[8];
#pragma unroll
        for (int qf2 = 0; qf2 < 8; qf2++) o[qf2] = (f32x4){0.f, 0.f, 0.f, 0.f};

        for (int l0 = 0; l0 < LQc; l0 += 32, ++it) {
            if (it < 31) STAGE_V((it + 1) & 1, it + 1);
            const ushort* v_ = pool + 32768 + (it & 1) * 4096;
            bf16x8 vb = *(const bf16x8*)&v_[wave * 512 + lh * 128 + l15 * 8];
            const int pcol = (l0 >> 3) + lh;     // chunk index of P col
#pragma unroll
            for (int qf2 = 0; qf2 < 8; qf2++) {
                bf16x8 pa = *(const bf16x8*)&Ps[qf2 * 4096 + pcol * 128 + l15 * 8];
                o[qf2] = __builtin_amdgcn_mfma_f32_16x16x32_bf16(pa, vb, o[qf2], 0, 0, 0);
            }
            VMCNT0;        // drain STAGE_V(it+1) before publishing
            __syncthreads();
        }
#pragma unroll
        for (int qf2 = 0; qf2 < 8; qf2++)
#pragma unroll
            for (int r = 0; r < 4; r++) {
                const int rowl = qf2 * 16 + lh * 4 + r;
                const int col = d0 + wave * 16 + l15;
                aout[((size_t)n * LQc + q0 + rowl) * Dc + col] = o[qf2][r];
            }
    }
}

// ---------------------------------------------------------------------------
extern "C" void kernel_launch(void* const* d_in, const int* in_sizes, int n_in,
                              void* d_out, int out_size, void* d_ws, size_t ws_size,
                              hipStream_t stream) {
    const float* queries    = (const float*)d_in[0];
    const float* keys       = (const float*)d_in[1];
    const float* values     = (const float*)d_in[2];
    const float* W_q        = (const float*)d_in[3];
    const float* W_k        = (const float*)d_in[4];
    const float* W_v        = (const float*)d_in[5];
    const float* W_o        = (const float*)d_in[6];
    const float* W_len      = (const float*)d_in[7];
    const float* b_len      = (const float*)d_in[8];
    const int*   valid_lens = (const int*)d_in[9];

    char* ws = (char*)d_ws;
    const size_t MB = 1024 * 1024;
    ushort* woBf = (ushort*)(ws + 128 * MB);          // 7 x 512 KB consecutive
    ushort* wl   = woBf + 262144;
    ushort* wqT  = wl   + 262144;
    ushort* wkT  = wqT  + 262144;
    ushort* wvT  = wkT  + 262144;
    ushort* Eq   = wvT  + 262144;                     // Eq[d][c]=sum_e Wq[e,d]Wk[e,c]
    ushort* G    = Eq   + 262144;                     // G[e][c]=sum_d Wo[e,d]Wv[d,c]
    ushort* t1k  = G    + 262144;                     // [32][256][512] bf16 (+ t1v contig)
    ushort* t1v  = t1k  + 4194304;
    ushort* k2   = t1v  + 4194304;
    ushort* v2T  = k2   + 4194304;

    const float alpha_q = 0.044194173824159216f;      // 1/sqrt(512)
    dim3 blk(256);

    // ---- all weight prep in one launch ----------------------------------
    prep_w<<<dim3(16, 16, 5), blk, 0, stream>>>(W_q, W_k, W_v, W_o, W_len,
                                                wqT, wkT, wvT, woBf, wl);
    // folded products
    gemm_bt<1, false, 0><<<dim3(4, 4, 1), blk, 0, stream>>>(
        wqT, wkT, Eq, nullptr, 512, 512, 512, 1.f, 0, 0, 0, 0);
    gemm_bt<1, false, 0><<<dim3(4, 4, 1), blk, 0, stream>>>(
        woBf, wvT, G, nullptr, 512, 512, 512, 1.f, 0, 0, 0, 0);

    // ---- fused length-projection from raw fp32 keys/values --------------
    lenproj_f32<<<dim3(4, 2, 64), blk, 0, stream>>>(wl, keys, values, b_len, t1k);

    // k2 = t1k @ Eq-contraction * alpha   (q-proj folded away)
    gemm_bt<1, false, 1><<<dim3(256), blk, 0, stream>>>(
        t1k, Eq, k2, nullptr, 8192, 512, 512, alpha_q, 0, 0, 0, 8);
    // v2T[b][e][q] = (t1v @ G^T)^T          (o-proj folded away)
    gemm_bt<2, false, 1><<<dim3(256), blk, 0, stream>>>(
        t1v, G, v2T, nullptr, 8192, 512, 512, 1.f, 0, 0, 0, 8);

    // ---- attention (raw fp32 queries, reg-Q, 8-wave blocks) -> d_out ----
    attn_mfma<<<dim3(512), dim3(512), 0, stream>>>(queries, k2, v2T, valid_lens,
                                                   (float*)d_out);
}

// Round 20
// 205.225 us; speedup vs baseline: 1.0903x; 1.0903x over previous
//
#include <hip/hip_runtime.h>
#include <math.h>

#define Bc  32
#define Hc  8
#define LQc 256
#define LVc 1024
#define Dc  512

// per-wave drain of outstanding global_load_lds BEFORE a barrier publishes
// the staged LDS to other waves (vmcnt is per-wave; R10/R12-proven).
#define VMCNT0 asm volatile("s_waitcnt vmcnt(0)" ::: "memory")

typedef short bf16x8 __attribute__((ext_vector_type(8)));
typedef float f32x4  __attribute__((ext_vector_type(4)));

__device__ __forceinline__ unsigned short f2bf(float x) {   // RNE fp32->bf16
    unsigned u = __builtin_bit_cast(unsigned, x);
    u = (u + 0x7fffu + ((u >> 16) & 1u)) >> 16;
    return (unsigned short)u;
}

__device__ __forceinline__ bf16x8 pack8(float4 a, float4 b) {
    bf16x8 r;
    r[0] = (short)f2bf(a.x); r[1] = (short)f2bf(a.y);
    r[2] = (short)f2bf(a.z); r[3] = (short)f2bf(a.w);
    r[4] = (short)f2bf(b.x); r[5] = (short)f2bf(b.y);
    r[6] = (short)f2bf(b.z); r[7] = (short)f2bf(b.w);
    return r;
}

__device__ __forceinline__ void gload16(const ushort* g, ushort* l) {
    __builtin_amdgcn_global_load_lds(
        (const __attribute__((address_space(1))) unsigned*)g,
        (__attribute__((address_space(3))) unsigned*)l, 16, 0, 0);
}

// ---------------------------------------------------------------------------
// All weight prep in ONE launch. grid (16,16,5), 256 thr.
// ---------------------------------------------------------------------------
__global__ __launch_bounds__(256) void prep_w(const float* __restrict__ Wq,
                                              const float* __restrict__ Wk,
                                              const float* __restrict__ Wv,
                                              const float* __restrict__ Wo,
                                              const float* __restrict__ Wl,
                                              ushort* __restrict__ wqT,
                                              ushort* __restrict__ wkT,
                                              ushort* __restrict__ wvT,
                                              ushort* __restrict__ woBf,
                                              ushort* __restrict__ wlBf) {
    const int z = blockIdx.z;
    if (z < 3) {
        __shared__ float t[32][33];
        const float* in = (z == 0) ? Wq : (z == 1) ? Wk : Wv;
        ushort* out = (z == 0) ? wqT : (z == 1) ? wkT : wvT;
        const int l0 = blockIdx.x * 32, d0 = blockIdx.y * 32;
        const int r = threadIdx.x >> 5, c = threadIdx.x & 31;
#pragma unroll
        for (int i = 0; i < 4; i++)
            t[r + 8 * i][c] = in[(size_t)(l0 + r + 8 * i) * 512 + d0 + c];
        __syncthreads();
#pragma unroll
        for (int i = 0; i < 4; i++)
            out[(size_t)(d0 + r + 8 * i) * 512 + l0 + c] = f2bf(t[c][r + 8 * i]);
    } else {
        const float* in = (z == 3) ? Wo : Wl;
        ushort* out = (z == 3) ? woBf : wlBf;
        const int i = (blockIdx.y * 16 + blockIdx.x) * 256 + threadIdx.x;
        float4 v = ((const float4*)in)[i];
        ushort4 o;
        o.x = f2bf(v.x); o.y = f2bf(v.y); o.z = f2bf(v.z); o.w = f2bf(v.w);
        ((ushort4*)out)[i] = o;
    }
}

// ---------------------------------------------------------------------------
// FUSED length-projection from raw fp32 keys/values (transpose in-LDS).
// t1[z][q][d] = b_len[q] + sum_l Wl[q][l] * X[z][l][d]    (bf16 out)
// ---------------------------------------------------------------------------
__global__ __launch_bounds__(256) void lenproj_f32(const ushort* __restrict__ wl,
                                                   const float* __restrict__ keys,
                                                   const float* __restrict__ vals,
                                                   const float* __restrict__ bias,
                                                   ushort* __restrict__ t1k) {
    __shared__ __align__(16) ushort Wls[4096];       // chunked A tile, 8 KB
    __shared__ __align__(16) float  Xsf[128 * 36];   // transposed X tile, 18 KB

    const int z = blockIdx.z;
    const float* X = ((z < 32) ? keys : vals) + (size_t)(z & 31) * LVc * Dc;
    ushort* C = t1k + (size_t)z * LQc * Dc;

    const int bm = blockIdx.y * 128;     // q
    const int bn = blockIdx.x * 128;     // d
    const int tid = threadIdx.x;
    const int wave = tid >> 6, l = tid & 63;
    const int wm = (wave >> 1) * 64, wn = (wave & 1) * 64;
    const int l15 = l & 15, lh = l >> 4;

    f32x4 acc[4][4];
#pragma unroll
    for (int m = 0; m < 4; m++)
#pragma unroll
        for (int n = 0; n < 4; n++) acc[m][n] = (f32x4){0.f, 0.f, 0.f, 0.f};

    const int lrow = tid >> 3;               // 0..31 (l within tile)
    const int dcol = (tid & 7) * 16;         // 0..112 (d within tile)

    for (int l0 = 0; l0 < LVc; l0 += 32) {
        gload16(wl + (size_t)(bm + wave * 16 + l15) * LVc + l0 + lh * 8,
                Wls + wave * 512);
        gload16(wl + (size_t)(bm + 64 + wave * 16 + l15) * LVc + l0 + lh * 8,
                Wls + (wave + 4) * 512);
        const float* xs = X + (size_t)(l0 + lrow) * Dc + bn + dcol;
        float4 xv0 = ((const float4*)xs)[0];
        float4 xv1 = ((const float4*)xs)[1];
        float4 xv2 = ((const float4*)xs)[2];
        float4 xv3 = ((const float4*)xs)[3];
        Xsf[(dcol + 0)  * 36 + lrow] = xv0.x;
        Xsf[(dcol + 1)  * 36 + lrow] = xv0.y;
        Xsf[(dcol + 2)  * 36 + lrow] = xv0.z;
        Xsf[(dcol + 3)  * 36 + lrow] = xv0.w;
        Xsf[(dcol + 4)  * 36 + lrow] = xv1.x;
        Xsf[(dcol + 5)  * 36 + lrow] = xv1.y;
        Xsf[(dcol + 6)  * 36 + lrow] = xv1.z;
        Xsf[(dcol + 7)  * 36 + lrow] = xv1.w;
        Xsf[(dcol + 8)  * 36 + lrow] = xv2.x;
        Xsf[(dcol + 9)  * 36 + lrow] = xv2.y;
        Xsf[(dcol + 10) * 36 + lrow] = xv2.z;
        Xsf[(dcol + 11) * 36 + lrow] = xv2.w;
        Xsf[(dcol + 12) * 36 + lrow] = xv3.x;
        Xsf[(dcol + 13) * 36 + lrow] = xv3.y;
        Xsf[(dcol + 14) * 36 + lrow] = xv3.z;
        Xsf[(dcol + 15) * 36 + lrow] = xv3.w;
        VMCNT0;
        __syncthreads();

        bf16x8 af[4], bfr[4];
#pragma unroll
        for (int m = 0; m < 4; m++)
            af[m] = *(const bf16x8*)&Wls[((wm >> 4) + m) * 512 + lh * 128 + l15 * 8];
#pragma unroll
        for (int n = 0; n < 4; n++) {
            const float* fb = &Xsf[(wn + n * 16 + l15) * 36 + lh * 8];
            float4 x0 = *(const float4*)fb;
            float4 x1 = *(const float4*)(fb + 4);
            bfr[n] = pack8(x0, x1);
        }
#pragma unroll
        for (int m = 0; m < 4; m++)
#pragma unroll
            for (int n = 0; n < 4; n++)
                acc[m][n] = __builtin_amdgcn_mfma_f32_16x16x32_bf16(
                    af[m], bfr[n], acc[m][n], 0, 0, 0);
        __syncthreads();
    }

#pragma unroll
    for (int m = 0; m < 4; m++)
#pragma unroll
        for (int r = 0; r < 4; r++) {
            const int row = bm + wm + m * 16 + lh * 4 + r;
            const float bv = bias[row];
#pragma unroll
            for (int n = 0; n < 4; n++) {
                const int col = bn + wn + n * 16 + l15;
                C[(size_t)row * Dc + col] = f2bf(acc[m][n][r] + bv);
            }
        }
}

// ---------------------------------------------------------------------------
// C[m,n] = alpha * sum_k A[m,k]*B[n,k] (+ bias)         (bf16 in, f32 accum)
// ---------------------------------------------------------------------------
template <int STORE, bool BIAS, int SWIZ>
__global__ __launch_bounds__(256) void gemm_bt(const ushort* __restrict__ A,
                                               const ushort* __restrict__ B,
                                               void* __restrict__ Cv,
                                               const float* __restrict__ bias,
                                               int M, int N, int K, float alpha,
                                               long sA, long sB, long sC,
                                               int byPerXcd) {
    __shared__ ushort As[128 * 32];
    __shared__ ushort Bs[128 * 32];
    const int z = blockIdx.z;
    A += (size_t)z * sA;
    B += (size_t)z * sB;
    float*  Cf = (float*)Cv  + (size_t)z * sC;
    ushort* Ch = (ushort*)Cv + (size_t)z * sC;

    int bm, bn;
    if constexpr (SWIZ) {
        const int bid = blockIdx.x;
        const int xcd = bid & 7, slot = bid >> 3;
        bm = (xcd * byPerXcd + (slot >> 2)) * 128;
        bn = (slot & 3) * 128;
    } else {
        bm = blockIdx.y * 128;
        bn = blockIdx.x * 128;
    }
    const int tid = threadIdx.x;
    const int wave = tid >> 6, l = tid & 63;
    const int wm = (wave >> 1) * 64, wn = (wave & 1) * 64;
    const int l15 = l & 15, lh = l >> 4;

    f32x4 acc[4][4];
#pragma unroll
    for (int m = 0; m < 4; m++)
#pragma unroll
        for (int n = 0; n < 4; n++) acc[m][n] = (f32x4){0.f, 0.f, 0.f, 0.f};

    const int srow = tid >> 2, scol = (tid & 3) * 8;
    ushort* ldsA = As + (wave * 16) * 32;
    ushort* ldsB = Bs + (wave * 16) * 32;
    const ushort* gA = A + (size_t)(bm + srow) * K + scol;
    const ushort* gB = B + (size_t)(bn + srow) * K + scol;

    for (int k0 = 0; k0 < K; k0 += 32) {
        gload16(gA + k0, ldsA);
        gload16(gA + k0 + (size_t)64 * K, ldsA + 64 * 32);
        gload16(gB + k0, ldsB);
        gload16(gB + k0 + (size_t)64 * K, ldsB + 64 * 32);
        VMCNT0;
        __syncthreads();
        bf16x8 af[4], bfr[4];
#pragma unroll
        for (int m = 0; m < 4; m++)
            af[m] = *(const bf16x8*)&As[(wm + m * 16 + l15) * 32 + lh * 8];
#pragma unroll
        for (int n = 0; n < 4; n++)
            bfr[n] = *(const bf16x8*)&Bs[(wn + n * 16 + l15) * 32 + lh * 8];
#pragma unroll
        for (int m = 0; m < 4; m++)
#pragma unroll
            for (int n = 0; n < 4; n++)
                acc[m][n] = __builtin_amdgcn_mfma_f32_16x16x32_bf16(
                    af[m], bfr[n], acc[m][n], 0, 0, 0);
        __syncthreads();
    }

    if constexpr (STORE == 2) {
#pragma unroll
        for (int m = 0; m < 4; m++) {
            const int row0 = bm + wm + m * 16 + lh * 4;
            const int bb = row0 >> 8, q = row0 & 255;
            float bv[4] = {0.f, 0.f, 0.f, 0.f};
            if constexpr (BIAS) {
#pragma unroll
                for (int r = 0; r < 4; r++) bv[r] = bias[q + r];
            }
#pragma unroll
            for (int n = 0; n < 4; n++) {
                const int col = bn + wn + n * 16 + l15;
                ushort4 o;
                o.x = f2bf(acc[m][n][0] * alpha + bv[0]);
                o.y = f2bf(acc[m][n][1] * alpha + bv[1]);
                o.z = f2bf(acc[m][n][2] * alpha + bv[2]);
                o.w = f2bf(acc[m][n][3] * alpha + bv[3]);
                *(ushort4*)&Ch[(size_t)bb * N * 256 + (size_t)col * 256 + q] = o;
            }
        }
    } else if constexpr (STORE == 1) {
#pragma unroll
        for (int m = 0; m < 4; m++)
#pragma unroll
            for (int r = 0; r < 4; r++) {
                const int row = bm + wm + m * 16 + lh * 4 + r;
                const float bv = BIAS ? bias[row & 255] : 0.f;
#pragma unroll
                for (int n = 0; n < 4; n++) {
                    const int col = bn + wn + n * 16 + l15;
                    Ch[(size_t)row * N + col] = f2bf(acc[m][n][r] * alpha + bv);
                }
            }
    } else {
#pragma unroll
        for (int m = 0; m < 4; m++)
#pragma unroll
            for (int r = 0; r < 4; r++) {
                const int row = bm + wm + m * 16 + lh * 4 + r;
                const float bv = BIAS ? bias[row & 255] : 0.f;
#pragma unroll
                for (int n = 0; n < 4; n++) {
                    const int col = bn + wn + n * 16 + l15;
                    Cf[(size_t)row * N + col] = acc[m][n][r] * alpha + bv;
                }
            }
    }
}

// ---------------------------------------------------------------------------
// Fused attention v12 = v11 with BK=64 phase A (8 barrier-iters, 2x compute
// per barrier). 512-thr blocks (8 waves), grid 512, pool 80KB -> 2 blk/CU.
// Phase A: K tile 256x64 (32KB), dbuf 2x32KB overlaying Ps region. Per wave:
//   4 K-DMAs, 2 Q-frag loads (k-slices), 32 MFMAs per iter.
// Phase B: unchanged from v11 (V dbuf 2x4KB at 64..72KB... [32768+] ushorts).
// Sync: stage -> compute -> VMCNT0 -> barrier (R12-proven). Arithmetic
// bit-identical to v11/v8.
// ---------------------------------------------------------------------------
__global__ __launch_bounds__(512, 2) void attn_mfma(const float* __restrict__ qf,
                                                    const ushort* __restrict__ k2,
                                                    const ushort* __restrict__ v2T,
                                                    const int* __restrict__ vlen,
                                                    float* __restrict__ aout) {
    __shared__ __align__(16) ushort pool[40960];     // 80 KB
    ushort* Ps = pool;                                // chunked P, [0, 32768)

    const int bid = blockIdx.x;
    const int xcd = bid & 7, pos = bid >> 3;      // 64 blocks per XCD
    const int b = xcd * 4 + (pos >> 4);           // 4 batches per XCD
    const int inner = pos & 15;
    const int h = inner >> 1, qh = inner & 1;
    const int n = b * 8 + h;
    const int q0 = qh * 128;

    const int tid = threadIdx.x, wave = tid >> 6, l = tid & 63;
    const int l15 = l & 15, lh = l >> 4;
    const int vl = vlen[b];

    const float*  qbase = qf  + ((size_t)n * LQc + q0) * Dc;
    const ushort* kbase = k2  + (size_t)b * LQc * Dc;
    const ushort* vbase = v2T + (size_t)b * LQc * Dc;

    // ---- phase A: scores 128x256; K BK=64 dbuf, Q direct to regs --------
    f32x4 sacc[16];
#pragma unroll
    for (int fn = 0; fn < 16; fn++) sacc[fn] = (f32x4){0.f, 0.f, 0.f, 0.f};

    auto STAGE_K = [&](int bi, int k0) {          // 4 DMAs per wave
        ushort* k_ = pool + bi * 16384;           // 32 KB per buffer
#pragma unroll
        for (int j = 0; j < 2; j++) {
            const int g = wave * 2 + j;           // group of 16 K-rows
            gload16(kbase + (size_t)(g * 16 + l15) * Dc + k0 + lh * 8,
                    k_ + g * 1024);
            gload16(kbase + (size_t)(g * 16 + l15) * Dc + k0 + 32 + lh * 8,
                    k_ + g * 1024 + 512);
        }
    };

    STAGE_K(0, 0);
    VMCNT0;
    __syncthreads();
    for (int t = 0; t < 8; ++t) {
        const int k0 = t * 64;
        if (t < 7) STAGE_K((t + 1) & 1, k0 + 64);
        const ushort* k_ = pool + (t & 1) * 16384;
#pragma unroll
        for (int s = 0; s < 2; ++s) {
            // Q fragment straight from global, rows 16w+l15, k-slice s
            const float* fb = qbase + (size_t)(wave * 16 + l15) * Dc + k0 + s * 32 + lh * 8;
            float4 x0 = *(const float4*)fb;
            float4 x1 = *(const float4*)(fb + 4);
            bf16x8 aq = pack8(x0, x1);
#pragma unroll
            for (int fn = 0; fn < 16; fn++) {
                bf16x8 bk = *(const bf16x8*)&k_[fn * 1024 + s * 512 + lh * 128 + l15 * 8];
                sacc[fn] = __builtin_amdgcn_mfma_f32_16x16x32_bf16(aq, bk, sacc[fn], 0, 0, 0);
            }
        }
        VMCNT0;            // drain STAGE_K(t+1) before publishing via barrier
        __syncthreads();
    }

    // ---- prefetch first V tile (hides under softmax VALU) ---------------
    auto STAGE_V = [&](int bi, int it) {          // 1 DMA per wave
        const int d0 = (it >> 3) * 128, l0 = (it & 7) * 32;
        ushort* v_ = pool + 32768 + bi * 4096;
        gload16(vbase + (size_t)(d0 + wave * 16 + l15) * LQc + l0 + lh * 8,
                v_ + wave * 512);
    };
    STAGE_V(0, 0);

    // ---- softmax: wave owns rows [16w,16w+16); normalize before write ---
#pragma unroll
    for (int r = 0; r < 4; r++) {
        const int rowl = wave * 16 + lh * 4 + r;
        float v[16];
        float rmax = -3.4e38f;
#pragma unroll
        for (int fn = 0; fn < 16; fn++) {
            const int col = fn * 16 + l15;
            float s = sacc[fn][r];
            v[fn] = (col < vl) ? s : -1e6f;
            rmax = fmaxf(rmax, v[fn]);
        }
        rmax = fmaxf(rmax, __shfl_xor(rmax, 1));
        rmax = fmaxf(rmax, __shfl_xor(rmax, 2));
        rmax = fmaxf(rmax, __shfl_xor(rmax, 4));
        rmax = fmaxf(rmax, __shfl_xor(rmax, 8));
        float rsum = 0.f;
#pragma unroll
        for (int fn = 0; fn < 16; fn++) {
            v[fn] = __expf(v[fn] - rmax);
            rsum += v[fn];
        }
        rsum += __shfl_xor(rsum, 1);
        rsum += __shfl_xor(rsum, 2);
        rsum += __shfl_xor(rsum, 4);
        rsum += __shfl_xor(rsum, 8);
        const float rinv = 1.0f / rsum;
        // chunked P write: row = wave*16+lh*4+r, col = fn*16+l15
        const int base = wave * 4096 + (lh * 4 + r) * 8 + (l15 & 7);
        const int chi = (l15 >> 3) * 128;
#pragma unroll
        for (int fn = 0; fn < 16; fn++)
            Ps[base + fn * 256 + chi] = f2bf(v[fn] * rinv);
    }
    VMCNT0;                // drain STAGE_V(0,0) before publishing
    __syncthreads();       // Ps visible + V tile 0 loaded

    // ---- phase B: out = P @ v2, 4 d-chunks of 128, 2-phase dbuf ---------
    int it = 0;
    for (int d0 = 0; d0 < Dc; d0 += 128) {
        f32x4 o[8];
#pragma unroll
        for (int qf2 = 0; qf2 < 8; qf2++) o[qf2] = (f32x4){0.f, 0.f, 0.f, 0.f};

        for (int l0 = 0; l0 < LQc; l0 += 32, ++it) {
            if (it < 31) STAGE_V((it + 1) & 1, it + 1);
            const ushort* v_ = pool + 32768 + (it & 1) * 4096;
            bf16x8 vb = *(const bf16x8*)&v_[wave * 512 + lh * 128 + l15 * 8];
            const int pcol = (l0 >> 3) + lh;     // chunk index of P col
#pragma unroll
            for (int qf2 = 0; qf2 < 8; qf2++) {
                bf16x8 pa = *(const bf16x8*)&Ps[qf2 * 4096 + pcol * 128 + l15 * 8];
                o[qf2] = __builtin_amdgcn_mfma_f32_16x16x32_bf16(pa, vb, o[qf2], 0, 0, 0);
            }
            VMCNT0;        // drain STAGE_V(it+1) before publishing
            __syncthreads();
        }
#pragma unroll
        for (int qf2 = 0; qf2 < 8; qf2++)
#pragma unroll
            for (int r = 0; r < 4; r++) {
                const int rowl = qf2 * 16 + lh * 4 + r;
                const int col = d0 + wave * 16 + l15;
                aout[((size_t)n * LQc + q0 + rowl) * Dc + col] = o[qf2][r];
            }
    }
}

// ---------------------------------------------------------------------------
extern "C" void kernel_launch(void* const* d_in, const int* in_sizes, int n_in,
                              void* d_out, int out_size, void* d_ws, size_t ws_size,
                              hipStream_t stream) {
    const float* queries    = (const float*)d_in[0];
    const float* keys       = (const float*)d_in[1];
    const float* values     = (const float*)d_in[2];
    const float* W_q        = (const float*)d_in[3];
    const float* W_k        = (const float*)d_in[4];
    const float* W_v        = (const float*)d_in[5];
    const float* W_o        = (const float*)d_in[6];
    const float* W_len      = (const float*)d_in[7];
    const float* b_len      = (const float*)d_in[8];
    const int*   valid_lens = (const int*)d_in[9];

    char* ws = (char*)d_ws;
    const size_t MB = 1024 * 1024;
    // fold operands ordered for one z-strided launch:
    //   A: [wqT | woBf], B: [wkT | wvT], C: [Eq | G]
    ushort* wqT  = (ushort*)(ws + 128 * MB);
    ushort* woBf = wqT  + 262144;
    ushort* wkT  = woBf + 262144;
    ushort* wvT  = wkT  + 262144;
    ushort* Eq   = wvT  + 262144;                     // Eq[d][c]=sum_e Wq[e,d]Wk[e,c]
    ushort* G    = Eq   + 262144;                     // G[e][c]=sum_d Wo[e,d]Wv[d,c]
    ushort* wl   = G    + 262144;
    ushort* t1k  = wl   + 262144;                     // [32][256][512] bf16 (+ t1v contig)
    ushort* t1v  = t1k  + 4194304;
    ushort* k2   = t1v  + 4194304;
    ushort* v2T  = k2   + 4194304;

    const float alpha_q = 0.044194173824159216f;      // 1/sqrt(512)
    dim3 blk(256);

    // ---- all weight prep in one launch ----------------------------------
    prep_w<<<dim3(16, 16, 5), blk, 0, stream>>>(W_q, W_k, W_v, W_o, W_len,
                                                wqT, wkT, wvT, woBf, wl);
    // folded products Eq and G in ONE z-strided launch
    gemm_bt<1, false, 0><<<dim3(4, 4, 2), blk, 0, stream>>>(
        wqT, wkT, Eq, nullptr, 512, 512, 512, 1.f, 262144, 262144, 262144, 0);

    // ---- fused length-projection from raw fp32 keys/values --------------
    lenproj_f32<<<dim3(4, 2, 64), blk, 0, stream>>>(wl, keys, values, b_len, t1k);

    // k2 = t1k @ Eq-contraction * alpha   (q-proj folded away)
    gemm_bt<1, false, 1><<<dim3(256), blk, 0, stream>>>(
        t1k, Eq, k2, nullptr, 8192, 512, 512, alpha_q, 0, 0, 0, 8);
    // v2T[b][e][q] = (t1v @ G^T)^T          (o-proj folded away)
    gemm_bt<2, false, 1><<<dim3(256), blk, 0, stream>>>(
        t1v, G, v2T, nullptr, 8192, 512, 512, 1.f, 0, 0, 0, 8);

    // ---- attention (raw fp32 queries, reg-Q, 8-wave blocks) -> d_out ----
    attn_mfma<<<dim3(512), dim3(512), 0, stream>>>(queries, k2, v2T, valid_lens,
                                                   (float*)d_out);
}

// Round 21
// 203.611 us; speedup vs baseline: 1.0989x; 1.0079x over previous
//
#include <hip/hip_runtime.h>
#include <math.h>

#define Bc  32
#define Hc  8
#define LQc 256
#define LVc 1024
#define Dc  512

// per-wave drain of outstanding global_load_lds BEFORE a barrier publishes
// the staged LDS to other waves (vmcnt is per-wave; R10/R12-proven).
#define VMCNT0 asm volatile("s_waitcnt vmcnt(0)" ::: "memory")
// counted per-wave drain (uniform global_load_lds stream, in-order retire):
// wait until <=N outstanding; used for per-wave-PRIVATE staging only.
#define VMCNT(N) asm volatile("s_waitcnt vmcnt(" #N ")" ::: "memory")

typedef short bf16x8 __attribute__((ext_vector_type(8)));
typedef float f32x4  __attribute__((ext_vector_type(4)));

__device__ __forceinline__ unsigned short f2bf(float x) {   // RNE fp32->bf16
    unsigned u = __builtin_bit_cast(unsigned, x);
    u = (u + 0x7fffu + ((u >> 16) & 1u)) >> 16;
    return (unsigned short)u;
}

__device__ __forceinline__ bf16x8 pack8(float4 a, float4 b) {
    bf16x8 r;
    r[0] = (short)f2bf(a.x); r[1] = (short)f2bf(a.y);
    r[2] = (short)f2bf(a.z); r[3] = (short)f2bf(a.w);
    r[4] = (short)f2bf(b.x); r[5] = (short)f2bf(b.y);
    r[6] = (short)f2bf(b.z); r[7] = (short)f2bf(b.w);
    return r;
}

__device__ __forceinline__ void gload16(const ushort* g, ushort* l) {
    __builtin_amdgcn_global_load_lds(
        (const __attribute__((address_space(1))) unsigned*)g,
        (__attribute__((address_space(3))) unsigned*)l, 16, 0, 0);
}

// ---------------------------------------------------------------------------
// All weight prep in ONE launch. grid (16,16,5), 256 thr.
// ---------------------------------------------------------------------------
__global__ __launch_bounds__(256) void prep_w(const float* __restrict__ Wq,
                                              const float* __restrict__ Wk,
                                              const float* __restrict__ Wv,
                                              const float* __restrict__ Wo,
                                              const float* __restrict__ Wl,
                                              ushort* __restrict__ wqT,
                                              ushort* __restrict__ wkT,
                                              ushort* __restrict__ wvT,
                                              ushort* __restrict__ woBf,
                                              ushort* __restrict__ wlBf) {
    const int z = blockIdx.z;
    if (z < 3) {
        __shared__ float t[32][33];
        const float* in = (z == 0) ? Wq : (z == 1) ? Wk : Wv;
        ushort* out = (z == 0) ? wqT : (z == 1) ? wkT : wvT;
        const int l0 = blockIdx.x * 32, d0 = blockIdx.y * 32;
        const int r = threadIdx.x >> 5, c = threadIdx.x & 31;
#pragma unroll
        for (int i = 0; i < 4; i++)
            t[r + 8 * i][c] = in[(size_t)(l0 + r + 8 * i) * 512 + d0 + c];
        __syncthreads();
#pragma unroll
        for (int i = 0; i < 4; i++)
            out[(size_t)(d0 + r + 8 * i) * 512 + l0 + c] = f2bf(t[c][r + 8 * i]);
    } else {
        const float* in = (z == 3) ? Wo : Wl;
        ushort* out = (z == 3) ? woBf : wlBf;
        const int i = (blockIdx.y * 16 + blockIdx.x) * 256 + threadIdx.x;
        float4 v = ((const float4*)in)[i];
        ushort4 o;
        o.x = f2bf(v.x); o.y = f2bf(v.y); o.z = f2bf(v.z); o.w = f2bf(v.w);
        ((ushort4*)out)[i] = o;
    }
}

// ---------------------------------------------------------------------------
// FUSED length-projection from raw fp32 keys/values (transpose in-LDS).
// t1[z][q][d] = b_len[q] + sum_l Wl[q][l] * X[z][l][d]    (bf16 out)
// ---------------------------------------------------------------------------
__global__ __launch_bounds__(256) void lenproj_f32(const ushort* __restrict__ wl,
                                                   const float* __restrict__ keys,
                                                   const float* __restrict__ vals,
                                                   const float* __restrict__ bias,
                                                   ushort* __restrict__ t1k) {
    __shared__ __align__(16) ushort Wls[4096];       // chunked A tile, 8 KB
    __shared__ __align__(16) float  Xsf[128 * 36];   // transposed X tile, 18 KB

    const int z = blockIdx.z;
    const float* X = ((z < 32) ? keys : vals) + (size_t)(z & 31) * LVc * Dc;
    ushort* C = t1k + (size_t)z * LQc * Dc;

    const int bm = blockIdx.y * 128;     // q
    const int bn = blockIdx.x * 128;     // d
    const int tid = threadIdx.x;
    const int wave = tid >> 6, l = tid & 63;
    const int wm = (wave >> 1) * 64, wn = (wave & 1) * 64;
    const int l15 = l & 15, lh = l >> 4;

    f32x4 acc[4][4];
#pragma unroll
    for (int m = 0; m < 4; m++)
#pragma unroll
        for (int n = 0; n < 4; n++) acc[m][n] = (f32x4){0.f, 0.f, 0.f, 0.f};

    const int lrow = tid >> 3;               // 0..31 (l within tile)
    const int dcol = (tid & 7) * 16;         // 0..112 (d within tile)

    for (int l0 = 0; l0 < LVc; l0 += 32) {
        gload16(wl + (size_t)(bm + wave * 16 + l15) * LVc + l0 + lh * 8,
                Wls + wave * 512);
        gload16(wl + (size_t)(bm + 64 + wave * 16 + l15) * LVc + l0 + lh * 8,
                Wls + (wave + 4) * 512);
        const float* xs = X + (size_t)(l0 + lrow) * Dc + bn + dcol;
        float4 xv0 = ((const float4*)xs)[0];
        float4 xv1 = ((const float4*)xs)[1];
        float4 xv2 = ((const float4*)xs)[2];
        float4 xv3 = ((const float4*)xs)[3];
        Xsf[(dcol + 0)  * 36 + lrow] = xv0.x;
        Xsf[(dcol + 1)  * 36 + lrow] = xv0.y;
        Xsf[(dcol + 2)  * 36 + lrow] = xv0.z;
        Xsf[(dcol + 3)  * 36 + lrow] = xv0.w;
        Xsf[(dcol + 4)  * 36 + lrow] = xv1.x;
        Xsf[(dcol + 5)  * 36 + lrow] = xv1.y;
        Xsf[(dcol + 6)  * 36 + lrow] = xv1.z;
        Xsf[(dcol + 7)  * 36 + lrow] = xv1.w;
        Xsf[(dcol + 8)  * 36 + lrow] = xv2.x;
        Xsf[(dcol + 9)  * 36 + lrow] = xv2.y;
        Xsf[(dcol + 10) * 36 + lrow] = xv2.z;
        Xsf[(dcol + 11) * 36 + lrow] = xv2.w;
        Xsf[(dcol + 12) * 36 + lrow] = xv3.x;
        Xsf[(dcol + 13) * 36 + lrow] = xv3.y;
        Xsf[(dcol + 14) * 36 + lrow] = xv3.z;
        Xsf[(dcol + 15) * 36 + lrow] = xv3.w;
        VMCNT0;
        __syncthreads();

        bf16x8 af[4], bfr[4];
#pragma unroll
        for (int m = 0; m < 4; m++)
            af[m] = *(const bf16x8*)&Wls[((wm >> 4) + m) * 512 + lh * 128 + l15 * 8];
#pragma unroll
        for (int n = 0; n < 4; n++) {
            const float* fb = &Xsf[(wn + n * 16 + l15) * 36 + lh * 8];
            float4 x0 = *(const float4*)fb;
            float4 x1 = *(const float4*)(fb + 4);
            bfr[n] = pack8(x0, x1);
        }
#pragma unroll
        for (int m = 0; m < 4; m++)
#pragma unroll
            for (int n = 0; n < 4; n++)
                acc[m][n] = __builtin_amdgcn_mfma_f32_16x16x32_bf16(
                    af[m], bfr[n], acc[m][n], 0, 0, 0);
        __syncthreads();
    }

#pragma unroll
    for (int m = 0; m < 4; m++)
#pragma unroll
        for (int r = 0; r < 4; r++) {
            const int row = bm + wm + m * 16 + lh * 4 + r;
            const float bv = bias[row];
#pragma unroll
            for (int n = 0; n < 4; n++) {
                const int col = bn + wn + n * 16 + l15;
                C[(size_t)row * Dc + col] = f2bf(acc[m][n][r] + bv);
            }
        }
}

// ---------------------------------------------------------------------------
// C[m,n] = alpha * sum_k A[m,k]*B[n,k] (+ bias)         (bf16 in, f32 accum)
// ---------------------------------------------------------------------------
template <int STORE, bool BIAS, int SWIZ>
__global__ __launch_bounds__(256) void gemm_bt(const ushort* __restrict__ A,
                                               const ushort* __restrict__ B,
                                               void* __restrict__ Cv,
                                               const float* __restrict__ bias,
                                               int M, int N, int K, float alpha,
                                               long sA, long sB, long sC,
                                               int byPerXcd) {
    __shared__ ushort As[128 * 32];
    __shared__ ushort Bs[128 * 32];
    const int z = blockIdx.z;
    A += (size_t)z * sA;
    B += (size_t)z * sB;
    float*  Cf = (float*)Cv  + (size_t)z * sC;
    ushort* Ch = (ushort*)Cv + (size_t)z * sC;

    int bm, bn;
    if constexpr (SWIZ) {
        const int bid = blockIdx.x;
        const int xcd = bid & 7, slot = bid >> 3;
        bm = (xcd * byPerXcd + (slot >> 2)) * 128;
        bn = (slot & 3) * 128;
    } else {
        bm = blockIdx.y * 128;
        bn = blockIdx.x * 128;
    }
    const int tid = threadIdx.x;
    const int wave = tid >> 6, l = tid & 63;
    const int wm = (wave >> 1) * 64, wn = (wave & 1) * 64;
    const int l15 = l & 15, lh = l >> 4;

    f32x4 acc[4][4];
#pragma unroll
    for (int m = 0; m < 4; m++)
#pragma unroll
        for (int n = 0; n < 4; n++) acc[m][n] = (f32x4){0.f, 0.f, 0.f, 0.f};

    const int srow = tid >> 2, scol = (tid & 3) * 8;
    ushort* ldsA = As + (wave * 16) * 32;
    ushort* ldsB = Bs + (wave * 16) * 32;
    const ushort* gA = A + (size_t)(bm + srow) * K + scol;
    const ushort* gB = B + (size_t)(bn + srow) * K + scol;

    for (int k0 = 0; k0 < K; k0 += 32) {
        gload16(gA + k0, ldsA);
        gload16(gA + k0 + (size_t)64 * K, ldsA + 64 * 32);
        gload16(gB + k0, ldsB);
        gload16(gB + k0 + (size_t)64 * K, ldsB + 64 * 32);
        VMCNT0;
        __syncthreads();
        bf16x8 af[4], bfr[4];
#pragma unroll
        for (int m = 0; m < 4; m++)
            af[m] = *(const bf16x8*)&As[(wm + m * 16 + l15) * 32 + lh * 8];
#pragma unroll
        for (int n = 0; n < 4; n++)
            bfr[n] = *(const bf16x8*)&Bs[(wn + n * 16 + l15) * 32 + lh * 8];
#pragma unroll
        for (int m = 0; m < 4; m++)
#pragma unroll
            for (int n = 0; n < 4; n++)
                acc[m][n] = __builtin_amdgcn_mfma_f32_16x16x32_bf16(
                    af[m], bfr[n], acc[m][n], 0, 0, 0);
        __syncthreads();
    }

    if constexpr (STORE == 2) {
#pragma unroll
        for (int m = 0; m < 4; m++) {
            const int row0 = bm + wm + m * 16 + lh * 4;
            const int bb = row0 >> 8, q = row0 & 255;
            float bv[4] = {0.f, 0.f, 0.f, 0.f};
            if constexpr (BIAS) {
#pragma unroll
                for (int r = 0; r < 4; r++) bv[r] = bias[q + r];
            }
#pragma unroll
            for (int n = 0; n < 4; n++) {
                const int col = bn + wn + n * 16 + l15;
                ushort4 o;
                o.x = f2bf(acc[m][n][0] * alpha + bv[0]);
                o.y = f2bf(acc[m][n][1] * alpha + bv[1]);
                o.z = f2bf(acc[m][n][2] * alpha + bv[2]);
                o.w = f2bf(acc[m][n][3] * alpha + bv[3]);
                *(ushort4*)&Ch[(size_t)bb * N * 256 + (size_t)col * 256 + q] = o;
            }
        }
    } else if constexpr (STORE == 1) {
#pragma unroll
        for (int m = 0; m < 4; m++)
#pragma unroll
            for (int r = 0; r < 4; r++) {
                const int row = bm + wm + m * 16 + lh * 4 + r;
                const float bv = BIAS ? bias[row & 255] : 0.f;
#pragma unroll
                for (int n = 0; n < 4; n++) {
                    const int col = bn + wn + n * 16 + l15;
                    Ch[(size_t)row * N + col] = f2bf(acc[m][n][r] * alpha + bv);
                }
            }
    } else {
#pragma unroll
        for (int m = 0; m < 4; m++)
#pragma unroll
            for (int r = 0; r < 4; r++) {
                const int row = bm + wm + m * 16 + lh * 4 + r;
                const float bv = BIAS ? bias[row & 255] : 0.f;
#pragma unroll
                for (int n = 0; n < 4; n++) {
                    const int col = bn + wn + n * 16 + l15;
                    Cf[(size_t)row * N + col] = acc[m][n][r] * alpha + bv;
                }
            }
    }
}

// ---------------------------------------------------------------------------
// Fused attention v13 = v12 with BARRIER-FREE phase B.
// Key fact: in phase B, wave w's MFMAs consume only the V rows wave w itself
// stages (v_[wave*512..]) -> V buffers are per-wave PRIVATE. So phase B needs
// no __syncthreads at all; per-wave counted VMCNT(1) (uniform gload_lds
// stream, in-order) drains V(it) while V(it+1) stays in flight. Waves drift
// freely and hide each other's latency. Phase A unchanged (K is shared).
// 512-thr blocks, pool 80KB -> 2 blk/CU. Arithmetic bit-identical.
// ---------------------------------------------------------------------------
__global__ __launch_bounds__(512, 2) void attn_mfma(const float* __restrict__ qf,
                                                    const ushort* __restrict__ k2,
                                                    const ushort* __restrict__ v2T,
                                                    const int* __restrict__ vlen,
                                                    float* __restrict__ aout) {
    __shared__ __align__(16) ushort pool[40960];     // 80 KB
    ushort* Ps = pool;                                // chunked P, [0, 32768)

    const int bid = blockIdx.x;
    const int xcd = bid & 7, pos = bid >> 3;      // 64 blocks per XCD
    const int b = xcd * 4 + (pos >> 4);           // 4 batches per XCD
    const int inner = pos & 15;
    const int h = inner >> 1, qh = inner & 1;
    const int n = b * 8 + h;
    const int q0 = qh * 128;

    const int tid = threadIdx.x, wave = tid >> 6, l = tid & 63;
    const int l15 = l & 15, lh = l >> 4;
    const int vl = vlen[b];

    const float*  qbase = qf  + ((size_t)n * LQc + q0) * Dc;
    const ushort* kbase = k2  + (size_t)b * LQc * Dc;
    const ushort* vbase = v2T + (size_t)b * LQc * Dc;

    // ---- phase A: scores 128x256; K BK=64 dbuf, Q direct to regs --------
    f32x4 sacc[16];
#pragma unroll
    for (int fn = 0; fn < 16; fn++) sacc[fn] = (f32x4){0.f, 0.f, 0.f, 0.f};

    auto STAGE_K = [&](int bi, int k0) {          // 4 DMAs per wave
        ushort* k_ = pool + bi * 16384;           // 32 KB per buffer
#pragma unroll
        for (int j = 0; j < 2; j++) {
            const int g = wave * 2 + j;           // group of 16 K-rows
            gload16(kbase + (size_t)(g * 16 + l15) * Dc + k0 + lh * 8,
                    k_ + g * 1024);
            gload16(kbase + (size_t)(g * 16 + l15) * Dc + k0 + 32 + lh * 8,
                    k_ + g * 1024 + 512);
        }
    };

    STAGE_K(0, 0);
    VMCNT0;
    __syncthreads();
    for (int t = 0; t < 8; ++t) {
        const int k0 = t * 64;
        if (t < 7) STAGE_K((t + 1) & 1, k0 + 64);
        const ushort* k_ = pool + (t & 1) * 16384;
#pragma unroll
        for (int s = 0; s < 2; ++s) {
            // Q fragment straight from global, rows 16w+l15, k-slice s
            const float* fb = qbase + (size_t)(wave * 16 + l15) * Dc + k0 + s * 32 + lh * 8;
            float4 x0 = *(const float4*)fb;
            float4 x1 = *(const float4*)(fb + 4);
            bf16x8 aq = pack8(x0, x1);
#pragma unroll
            for (int fn = 0; fn < 16; fn++) {
                bf16x8 bk = *(const bf16x8*)&k_[fn * 1024 + s * 512 + lh * 128 + l15 * 8];
                sacc[fn] = __builtin_amdgcn_mfma_f32_16x16x32_bf16(aq, bk, sacc[fn], 0, 0, 0);
            }
        }
        VMCNT0;            // drain STAGE_K(t+1) before publishing via barrier
        __syncthreads();
    }

    // ---- prefetch first V tile (per-wave private; hides under softmax) --
    auto STAGE_V = [&](int bi, int it) {          // 1 DMA per wave
        const int d0 = (it >> 3) * 128, l0 = (it & 7) * 32;
        ushort* v_ = pool + 32768 + bi * 4096;
        gload16(vbase + (size_t)(d0 + wave * 16 + l15) * LQc + l0 + lh * 8,
                v_ + wave * 512);
    };
    STAGE_V(0, 0);

    // ---- softmax: wave owns rows [16w,16w+16); normalize before write ---
#pragma unroll
    for (int r = 0; r < 4; r++) {
        const int rowl = wave * 16 + lh * 4 + r;
        float v[16];
        float rmax = -3.4e38f;
#pragma unroll
        for (int fn = 0; fn < 16; fn++) {
            const int col = fn * 16 + l15;
            float s = sacc[fn][r];
            v[fn] = (col < vl) ? s : -1e6f;
            rmax = fmaxf(rmax, v[fn]);
        }
        rmax = fmaxf(rmax, __shfl_xor(rmax, 1));
        rmax = fmaxf(rmax, __shfl_xor(rmax, 2));
        rmax = fmaxf(rmax, __shfl_xor(rmax, 4));
        rmax = fmaxf(rmax, __shfl_xor(rmax, 8));
        float rsum = 0.f;
#pragma unroll
        for (int fn = 0; fn < 16; fn++) {
            v[fn] = __expf(v[fn] - rmax);
            rsum += v[fn];
        }
        rsum += __shfl_xor(rsum, 1);
        rsum += __shfl_xor(rsum, 2);
        rsum += __shfl_xor(rsum, 4);
        rsum += __shfl_xor(rsum, 8);
        const float rinv = 1.0f / rsum;
        // chunked P write: row = wave*16+lh*4+r, col = fn*16+l15
        const int base = wave * 4096 + (lh * 4 + r) * 8 + (l15 & 7);
        const int chi = (l15 >> 3) * 128;
#pragma unroll
        for (int fn = 0; fn < 16; fn++)
            Ps[base + fn * 256 + chi] = f2bf(v[fn] * rinv);
    }
    VMCNT0;                // V(0) landed (also any stragglers)
    __syncthreads();       // Ps published; ONLY barrier after this point: none

    // ---- phase B: out = P @ v2 -- BARRIER-FREE (V is per-wave private) --
    int it = 0;
    for (int d0 = 0; d0 < Dc; d0 += 128) {
        f32x4 o[8];
#pragma unroll
        for (int qf2 = 0; qf2 < 8; qf2++) o[qf2] = (f32x4){0.f, 0.f, 0.f, 0.f};

        for (int l0 = 0; l0 < LQc; l0 += 32, ++it) {
            if (it < 31) {
                STAGE_V((it + 1) & 1, it + 1);
                VMCNT(1);  // drain V(it) (older, in-order); V(it+1) in flight
            } else {
                VMCNT0;    // last tile: drain everything
            }
            const ushort* v_ = pool + 32768 + (it & 1) * 4096;
            bf16x8 vb = *(const bf16x8*)&v_[wave * 512 + lh * 128 + l15 * 8];
            const int pcol = (l0 >> 3) + lh;     // chunk index of P col
#pragma unroll
            for (int qf2 = 0; qf2 < 8; qf2++) {
                bf16x8 pa = *(const bf16x8*)&Ps[qf2 * 4096 + pcol * 128 + l15 * 8];
                o[qf2] = __builtin_amdgcn_mfma_f32_16x16x32_bf16(pa, vb, o[qf2], 0, 0, 0);
            }
        }
#pragma unroll
        for (int qf2 = 0; qf2 < 8; qf2++)
#pragma unroll
            for (int r = 0; r < 4; r++) {
                const int rowl = qf2 * 16 + lh * 4 + r;
                const int col = d0 + wave * 16 + l15;
                aout[((size_t)n * LQc + q0 + rowl) * Dc + col] = o[qf2][r];
            }
    }
}

// ---------------------------------------------------------------------------
extern "C" void kernel_launch(void* const* d_in, const int* in_sizes, int n_in,
                              void* d_out, int out_size, void* d_ws, size_t ws_size,
                              hipStream_t stream) {
    const float* queries    = (const float*)d_in[0];
    const float* keys       = (const float*)d_in[1];
    const float* values     = (const float*)d_in[2];
    const float* W_q        = (const float*)d_in[3];
    const float* W_k        = (const float*)d_in[4];
    const float* W_v        = (const float*)d_in[5];
    const float* W_o        = (const float*)d_in[6];
    const float* W_len      = (const float*)d_in[7];
    const float* b_len      = (const float*)d_in[8];
    const int*   valid_lens = (const int*)d_in[9];

    char* ws = (char*)d_ws;
    const size_t MB = 1024 * 1024;
    // fold operands ordered for one z-strided launch:
    //   A: [wqT | woBf], B: [wkT | wvT], C: [Eq | G]
    ushort* wqT  = (ushort*)(ws + 128 * MB);
    ushort* woBf = wqT  + 262144;
    ushort* wkT  = woBf + 262144;
    ushort* wvT  = wkT  + 262144;
    ushort* Eq   = wvT  + 262144;                     // Eq[d][c]=sum_e Wq[e,d]Wk[e,c]
    ushort* G    = Eq   + 262144;                     // G[e][c]=sum_d Wo[e,d]Wv[d,c]
    ushort* wl   = G    + 262144;
    ushort* t1k  = wl   + 262144;                     // [32][256][512] bf16 (+ t1v contig)
    ushort* t1v  = t1k  + 4194304;
    ushort* k2   = t1v  + 4194304;
    ushort* v2T  = k2   + 4194304;

    const float alpha_q = 0.044194173824159216f;      // 1/sqrt(512)
    dim3 blk(256);

    // ---- all weight prep in one launch ----------------------------------
    prep_w<<<dim3(16, 16, 5), blk, 0, stream>>>(W_q, W_k, W_v, W_o, W_len,
                                                wqT, wkT, wvT, woBf, wl);
    // folded products Eq and G in ONE z-strided launch
    gemm_bt<1, false, 0><<<dim3(4, 4, 2), blk, 0, stream>>>(
        wqT, wkT, Eq, nullptr, 512, 512, 512, 1.f, 262144, 262144, 262144, 0);

    // ---- fused length-projection from raw fp32 keys/values --------------
    lenproj_f32<<<dim3(4, 2, 64), blk, 0, stream>>>(wl, keys, values, b_len, t1k);

    // k2 = t1k @ Eq-contraction * alpha   (q-proj folded away)
    gemm_bt<1, false, 1><<<dim3(256), blk, 0, stream>>>(
        t1k, Eq, k2, nullptr, 8192, 512, 512, alpha_q, 0, 0, 0, 8);
    // v2T[b][e][q] = (t1v @ G^T)^T          (o-proj folded away)
    gemm_bt<2, false, 1><<<dim3(256), blk, 0, stream>>>(
        t1v, G, v2T, nullptr, 8192, 512, 512, 1.f, 0, 0, 0, 8);

    // ---- attention (raw fp32 queries, reg-Q, 8-wave blocks) -> d_out ----
    attn_mfma<<<dim3(512), dim3(512), 0, stream>>>(queries, k2, v2T, valid_lens,
                                                   (float*)d_out);
}

// Round 22
// 203.017 us; speedup vs baseline: 1.1022x; 1.0029x over previous
//
#include <hip/hip_runtime.h>
#include <math.h>

#define Bc  32
#define Hc  8
#define LQc 256
#define LVc 1024
#define Dc  512

// per-wave drain of outstanding vmem BEFORE a barrier publishes staged LDS
// (vmcnt is per-wave; R10/R12-proven).
#define VMCNT0 asm volatile("s_waitcnt vmcnt(0)" ::: "memory")
// counted per-wave drain: wait until <=N vmem ops outstanding. vmcnt
// retires in issue order; MUST be followed by sched_barrier(0) so the
// compiler cannot hoist dependent-free ds_reads above it (R18 lesson).
#define VMCNT(N) asm volatile("s_waitcnt vmcnt(" #N ")" ::: "memory")
#define SCHEDB __builtin_amdgcn_sched_barrier(0)

typedef short bf16x8 __attribute__((ext_vector_type(8)));
typedef float f32x4  __attribute__((ext_vector_type(4)));

__device__ __forceinline__ unsigned short f2bf(float x) {   // RNE fp32->bf16
    unsigned u = __builtin_bit_cast(unsigned, x);
    u = (u + 0x7fffu + ((u >> 16) & 1u)) >> 16;
    return (unsigned short)u;
}

__device__ __forceinline__ bf16x8 pack8(float4 a, float4 b) {
    bf16x8 r;
    r[0] = (short)f2bf(a.x); r[1] = (short)f2bf(a.y);
    r[2] = (short)f2bf(a.z); r[3] = (short)f2bf(a.w);
    r[4] = (short)f2bf(b.x); r[5] = (short)f2bf(b.y);
    r[6] = (short)f2bf(b.z); r[7] = (short)f2bf(b.w);
    return r;
}

__device__ __forceinline__ void gload16(const ushort* g, ushort* l) {
    __builtin_amdgcn_global_load_lds(
        (const __attribute__((address_space(1))) unsigned*)g,
        (__attribute__((address_space(3))) unsigned*)l, 16, 0, 0);
}

// ---------------------------------------------------------------------------
// All weight prep in ONE launch. grid (16,16,5), 256 thr.
// ---------------------------------------------------------------------------
__global__ __launch_bounds__(256) void prep_w(const float* __restrict__ Wq,
                                              const float* __restrict__ Wk,
                                              const float* __restrict__ Wv,
                                              const float* __restrict__ Wo,
                                              const float* __restrict__ Wl,
                                              ushort* __restrict__ wqT,
                                              ushort* __restrict__ wkT,
                                              ushort* __restrict__ wvT,
                                              ushort* __restrict__ woBf,
                                              ushort* __restrict__ wlBf) {
    const int z = blockIdx.z;
    if (z < 3) {
        __shared__ float t[32][33];
        const float* in = (z == 0) ? Wq : (z == 1) ? Wk : Wv;
        ushort* out = (z == 0) ? wqT : (z == 1) ? wkT : wvT;
        const int l0 = blockIdx.x * 32, d0 = blockIdx.y * 32;
        const int r = threadIdx.x >> 5, c = threadIdx.x & 31;
#pragma unroll
        for (int i = 0; i < 4; i++)
            t[r + 8 * i][c] = in[(size_t)(l0 + r + 8 * i) * 512 + d0 + c];
        __syncthreads();
#pragma unroll
        for (int i = 0; i < 4; i++)
            out[(size_t)(d0 + r + 8 * i) * 512 + l0 + c] = f2bf(t[c][r + 8 * i]);
    } else {
        const float* in = (z == 3) ? Wo : Wl;
        ushort* out = (z == 3) ? woBf : wlBf;
        const int i = (blockIdx.y * 16 + blockIdx.x) * 256 + threadIdx.x;
        float4 v = ((const float4*)in)[i];
        ushort4 o;
        o.x = f2bf(v.x); o.y = f2bf(v.y); o.z = f2bf(v.z); o.w = f2bf(v.w);
        ((ushort4*)out)[i] = o;
    }
}

// ---------------------------------------------------------------------------
// FUSED length-projection from raw fp32 keys/values (transpose in-LDS).
// t1[z][q][d] = b_len[q] + sum_l Wl[q][l] * X[z][l][d]    (bf16 out)
// ---------------------------------------------------------------------------
__global__ __launch_bounds__(256) void lenproj_f32(const ushort* __restrict__ wl,
                                                   const float* __restrict__ keys,
                                                   const float* __restrict__ vals,
                                                   const float* __restrict__ bias,
                                                   ushort* __restrict__ t1k) {
    __shared__ __align__(16) ushort Wls[4096];       // chunked A tile, 8 KB
    __shared__ __align__(16) float  Xsf[128 * 36];   // transposed X tile, 18 KB

    const int z = blockIdx.z;
    const float* X = ((z < 32) ? keys : vals) + (size_t)(z & 31) * LVc * Dc;
    ushort* C = t1k + (size_t)z * LQc * Dc;

    const int bm = blockIdx.y * 128;     // q
    const int bn = blockIdx.x * 128;     // d
    const int tid = threadIdx.x;
    const int wave = tid >> 6, l = tid & 63;
    const int wm = (wave >> 1) * 64, wn = (wave & 1) * 64;
    const int l15 = l & 15, lh = l >> 4;

    f32x4 acc[4][4];
#pragma unroll
    for (int m = 0; m < 4; m++)
#pragma unroll
        for (int n = 0; n < 4; n++) acc[m][n] = (f32x4){0.f, 0.f, 0.f, 0.f};

    const int lrow = tid >> 3;               // 0..31 (l within tile)
    const int dcol = (tid & 7) * 16;         // 0..112 (d within tile)

    for (int l0 = 0; l0 < LVc; l0 += 32) {
        gload16(wl + (size_t)(bm + wave * 16 + l15) * LVc + l0 + lh * 8,
                Wls + wave * 512);
        gload16(wl + (size_t)(bm + 64 + wave * 16 + l15) * LVc + l0 + lh * 8,
                Wls + (wave + 4) * 512);
        const float* xs = X + (size_t)(l0 + lrow) * Dc + bn + dcol;
        float4 xv0 = ((const float4*)xs)[0];
        float4 xv1 = ((const float4*)xs)[1];
        float4 xv2 = ((const float4*)xs)[2];
        float4 xv3 = ((const float4*)xs)[3];
        Xsf[(dcol + 0)  * 36 + lrow] = xv0.x;
        Xsf[(dcol + 1)  * 36 + lrow] = xv0.y;
        Xsf[(dcol + 2)  * 36 + lrow] = xv0.z;
        Xsf[(dcol + 3)  * 36 + lrow] = xv0.w;
        Xsf[(dcol + 4)  * 36 + lrow] = xv1.x;
        Xsf[(dcol + 5)  * 36 + lrow] = xv1.y;
        Xsf[(dcol + 6)  * 36 + lrow] = xv1.z;
        Xsf[(dcol + 7)  * 36 + lrow] = xv1.w;
        Xsf[(dcol + 8)  * 36 + lrow] = xv2.x;
        Xsf[(dcol + 9)  * 36 + lrow] = xv2.y;
        Xsf[(dcol + 10) * 36 + lrow] = xv2.z;
        Xsf[(dcol + 11) * 36 + lrow] = xv2.w;
        Xsf[(dcol + 12) * 36 + lrow] = xv3.x;
        Xsf[(dcol + 13) * 36 + lrow] = xv3.y;
        Xsf[(dcol + 14) * 36 + lrow] = xv3.z;
        Xsf[(dcol + 15) * 36 + lrow] = xv3.w;
        VMCNT0;
        __syncthreads();

        bf16x8 af[4], bfr[4];
#pragma unroll
        for (int m = 0; m < 4; m++)
            af[m] = *(const bf16x8*)&Wls[((wm >> 4) + m) * 512 + lh * 128 + l15 * 8];
#pragma unroll
        for (int n = 0; n < 4; n++) {
            const float* fb = &Xsf[(wn + n * 16 + l15) * 36 + lh * 8];
            float4 x0 = *(const float4*)fb;
            float4 x1 = *(const float4*)(fb + 4);
            bfr[n] = pack8(x0, x1);
        }
#pragma unroll
        for (int m = 0; m < 4; m++)
#pragma unroll
            for (int n = 0; n < 4; n++)
                acc[m][n] = __builtin_amdgcn_mfma_f32_16x16x32_bf16(
                    af[m], bfr[n], acc[m][n], 0, 0, 0);
        __syncthreads();
    }

#pragma unroll
    for (int m = 0; m < 4; m++)
#pragma unroll
        for (int r = 0; r < 4; r++) {
            const int row = bm + wm + m * 16 + lh * 4 + r;
            const float bv = bias[row];
#pragma unroll
            for (int n = 0; n < 4; n++) {
                const int col = bn + wn + n * 16 + l15;
                C[(size_t)row * Dc + col] = f2bf(acc[m][n][r] + bv);
            }
        }
}

// ---------------------------------------------------------------------------
// C[m,n] = alpha * sum_k A[m,k]*B[n,k] (+ bias)         (bf16 in, f32 accum)
// ---------------------------------------------------------------------------
template <int STORE, bool BIAS, int SWIZ>
__global__ __launch_bounds__(256) void gemm_bt(const ushort* __restrict__ A,
                                               const ushort* __restrict__ B,
                                               void* __restrict__ Cv,
                                               const float* __restrict__ bias,
                                               int M, int N, int K, float alpha,
                                               long sA, long sB, long sC,
                                               int byPerXcd) {
    __shared__ ushort As[128 * 32];
    __shared__ ushort Bs[128 * 32];
    const int z = blockIdx.z;
    A += (size_t)z * sA;
    B += (size_t)z * sB;
    float*  Cf = (float*)Cv  + (size_t)z * sC;
    ushort* Ch = (ushort*)Cv + (size_t)z * sC;

    int bm, bn;
    if constexpr (SWIZ) {
        const int bid = blockIdx.x;
        const int xcd = bid & 7, slot = bid >> 3;
        bm = (xcd * byPerXcd + (slot >> 2)) * 128;
        bn = (slot & 3) * 128;
    } else {
        bm = blockIdx.y * 128;
        bn = blockIdx.x * 128;
    }
    const int tid = threadIdx.x;
    const int wave = tid >> 6, l = tid & 63;
    const int wm = (wave >> 1) * 64, wn = (wave & 1) * 64;
    const int l15 = l & 15, lh = l >> 4;

    f32x4 acc[4][4];
#pragma unroll
    for (int m = 0; m < 4; m++)
#pragma unroll
        for (int n = 0; n < 4; n++) acc[m][n] = (f32x4){0.f, 0.f, 0.f, 0.f};

    const int srow = tid >> 2, scol = (tid & 3) * 8;
    ushort* ldsA = As + (wave * 16) * 32;
    ushort* ldsB = Bs + (wave * 16) * 32;
    const ushort* gA = A + (size_t)(bm + srow) * K + scol;
    const ushort* gB = B + (size_t)(bn + srow) * K + scol;

    for (int k0 = 0; k0 < K; k0 += 32) {
        gload16(gA + k0, ldsA);
        gload16(gA + k0 + (size_t)64 * K, ldsA + 64 * 32);
        gload16(gB + k0, ldsB);
        gload16(gB + k0 + (size_t)64 * K, ldsB + 64 * 32);
        VMCNT0;
        __syncthreads();
        bf16x8 af[4], bfr[4];
#pragma unroll
        for (int m = 0; m < 4; m++)
            af[m] = *(const bf16x8*)&As[(wm + m * 16 + l15) * 32 + lh * 8];
#pragma unroll
        for (int n = 0; n < 4; n++)
            bfr[n] = *(const bf16x8*)&Bs[(wn + n * 16 + l15) * 32 + lh * 8];
#pragma unroll
        for (int m = 0; m < 4; m++)
#pragma unroll
            for (int n = 0; n < 4; n++)
                acc[m][n] = __builtin_amdgcn_mfma_f32_16x16x32_bf16(
                    af[m], bfr[n], acc[m][n], 0, 0, 0);
        __syncthreads();
    }

    if constexpr (STORE == 2) {
#pragma unroll
        for (int m = 0; m < 4; m++) {
            const int row0 = bm + wm + m * 16 + lh * 4;
            const int bb = row0 >> 8, q = row0 & 255;
            float bv[4] = {0.f, 0.f, 0.f, 0.f};
            if constexpr (BIAS) {
#pragma unroll
                for (int r = 0; r < 4; r++) bv[r] = bias[q + r];
            }
#pragma unroll
            for (int n = 0; n < 4; n++) {
                const int col = bn + wn + n * 16 + l15;
                ushort4 o;
                o.x = f2bf(acc[m][n][0] * alpha + bv[0]);
                o.y = f2bf(acc[m][n][1] * alpha + bv[1]);
                o.z = f2bf(acc[m][n][2] * alpha + bv[2]);
                o.w = f2bf(acc[m][n][3] * alpha + bv[3]);
                *(ushort4*)&Ch[(size_t)bb * N * 256 + (size_t)col * 256 + q] = o;
            }
        }
    } else if constexpr (STORE == 1) {
#pragma unroll
        for (int m = 0; m < 4; m++)
#pragma unroll
            for (int r = 0; r < 4; r++) {
                const int row = bm + wm + m * 16 + lh * 4 + r;
                const float bv = BIAS ? bias[row & 255] : 0.f;
#pragma unroll
                for (int n = 0; n < 4; n++) {
                    const int col = bn + wn + n * 16 + l15;
                    Ch[(size_t)row * N + col] = f2bf(acc[m][n][r] * alpha + bv);
                }
            }
    } else {
#pragma unroll
        for (int m = 0; m < 4; m++)
#pragma unroll
            for (int r = 0; r < 4; r++) {
                const int row = bm + wm + m * 16 + lh * 4 + r;
                const float bv = BIAS ? bias[row & 255] : 0.f;
#pragma unroll
                for (int n = 0; n < 4; n++) {
                    const int col = bn + wn + n * 16 + l15;
                    Cf[(size_t)row * N + col] = acc[m][n][r] * alpha + bv;
                }
            }
    }
}

// ---------------------------------------------------------------------------
// Fused attention v14: depth-2 counted pipeline in phase A with an EXPLICIT
// VMCNT(N)+sched_barrier fence before the MFMA cluster (the R18 race was the
// compiler hoisting dependence-free ds_reads above the implicit wait; the
// fence forbids that). BK=32, 3 K-buffers (48KB inside Ps region), Q regs
// ping-pong. Per iter: issue K(t+2) then Q(t+1) (order pinned); wait drains
// through Q(t) -> also K(t+1), which the end-of-iter barrier then publishes;
// K(t+2)+Q(t+1) stay in flight (1 full iteration of latency hiding each).
// Phase B barrier-free (per-wave-private V, R21-proven). 512-thr blocks,
// pool 80KB -> 2 blk/CU. Arithmetic bit-identical to v8..v13.
// ---------------------------------------------------------------------------
__global__ __launch_bounds__(512, 2) void attn_mfma(const float* __restrict__ qf,
                                                    const ushort* __restrict__ k2,
                                                    const ushort* __restrict__ v2T,
                                                    const int* __restrict__ vlen,
                                                    float* __restrict__ aout) {
    __shared__ __align__(16) ushort pool[40960];     // 80 KB
    ushort* Ps = pool;                                // chunked P, [0, 32768)

    const int bid = blockIdx.x;
    const int xcd = bid & 7, pos = bid >> 3;      // 64 blocks per XCD
    const int b = xcd * 4 + (pos >> 4);           // 4 batches per XCD
    const int inner = pos & 15;
    const int h = inner >> 1, qh = inner & 1;
    const int n = b * 8 + h;
    const int q0 = qh * 128;

    const int tid = threadIdx.x, wave = tid >> 6, l = tid & 63;
    const int l15 = l & 15, lh = l >> 4;
    const int vl = vlen[b];

    const float*  qbase = qf  + ((size_t)n * LQc + q0) * Dc;
    const ushort* kbase = k2  + (size_t)b * LQc * Dc;
    const ushort* vbase = v2T + (size_t)b * LQc * Dc;

    // ---- phase A: scores 128x256; 3-buf K (BK=32), depth-2 K and Q ------
    f32x4 sacc[16];
#pragma unroll
    for (int fn = 0; fn < 16; fn++) sacc[fn] = (f32x4){0.f, 0.f, 0.f, 0.f};

    auto STAGE_K = [&](int bi, int k0) {          // 2 DMAs per wave
        ushort* k_ = pool + bi * 8192;            // 16 KB per buffer
#pragma unroll
        for (int j = 0; j < 2; j++) {
            const int g = wave * 2 + j;           // group of 16 K-rows
            gload16(kbase + (size_t)(g * 16 + l15) * Dc + k0 + lh * 8,
                    k_ + g * 512);
        }
    };
    auto QL = [&](int k0, float4* q) {            // 2 loads per lane
        const float* fb = qbase + (size_t)(wave * 16 + l15) * Dc + k0 + lh * 8;
        q[0] = *(const float4*)fb;
        q[1] = *(const float4*)(fb + 4);
    };

    float4 qr[2][2];
    STAGE_K(0, 0);
    STAGE_K(1, 32);
    SCHEDB;                      // K(0),K(1) older than Q(0)
    QL(0, qr[0]);
    VMCNT(4);                    // drain K(0); K(1)+Q(0) stay in flight
    SCHEDB;
    __syncthreads();             // publish K(0)

#pragma unroll
    for (int t = 0; t < 16; ++t) {
        if (t + 2 < 16) STAGE_K((t + 2) % 3, (t + 2) * 32);
        SCHEDB;                  // pin K(t+2) older than Q(t+1)
        if (t + 1 < 16) QL((t + 1) * 32, qr[(t + 1) & 1]);
        // fence: drain through Q(t) (=> K(t+1) too); keep K(t+2),Q(t+1) flying
        if (t < 14)      { VMCNT(4); }
        else if (t == 14){ VMCNT(2); }
        else             { VMCNT(0); }
        SCHEDB;                  // ds_reads below MUST NOT hoist above fence
        bf16x8 aq = pack8(qr[t & 1][0], qr[t & 1][1]);
        const ushort* k_ = pool + (t % 3) * 8192;
#pragma unroll
        for (int fn = 0; fn < 16; fn++) {
            bf16x8 bk = *(const bf16x8*)&k_[fn * 512 + lh * 128 + l15 * 8];
            sacc[fn] = __builtin_amdgcn_mfma_f32_16x16x32_bf16(aq, bk, sacc[fn], 0, 0, 0);
        }
        __syncthreads();         // publish K(t+1) (already drained by fence)
    }

    // ---- prefetch first V tile (per-wave private; hides under softmax) --
    auto STAGE_V = [&](int bi, int it) {          // 1 DMA per wave
        const int d0 = (it >> 3) * 128, l0 = (it & 7) * 32;
        ushort* v_ = pool + 32768 + bi * 4096;
        gload16(vbase + (size_t)(d0 + wave * 16 + l15) * LQc + l0 + lh * 8,
                v_ + wave * 512);
    };
    STAGE_V(0, 0);

    // ---- softmax: wave owns rows [16w,16w+16); normalize before write ---
#pragma unroll
    for (int r = 0; r < 4; r++) {
        const int rowl = wave * 16 + lh * 4 + r;
        float v[16];
        float rmax = -3.4e38f;
#pragma unroll
        for (int fn = 0; fn < 16; fn++) {
            const int col = fn * 16 + l15;
            float s = sacc[fn][r];
            v[fn] = (col < vl) ? s : -1e6f;
            rmax = fmaxf(rmax, v[fn]);
        }
        rmax = fmaxf(rmax, __shfl_xor(rmax, 1));
        rmax = fmaxf(rmax, __shfl_xor(rmax, 2));
        rmax = fmaxf(rmax, __shfl_xor(rmax, 4));
        rmax = fmaxf(rmax, __shfl_xor(rmax, 8));
        float rsum = 0.f;
#pragma unroll
        for (int fn = 0; fn < 16; fn++) {
            v[fn] = __expf(v[fn] - rmax);
            rsum += v[fn];
        }
        rsum += __shfl_xor(rsum, 1);
        rsum += __shfl_xor(rsum, 2);
        rsum += __shfl_xor(rsum, 4);
        rsum += __shfl_xor(rsum, 8);
        const float rinv = 1.0f / rsum;
        // chunked P write: row = wave*16+lh*4+r, col = fn*16+l15
        const int base = wave * 4096 + (lh * 4 + r) * 8 + (l15 & 7);
        const int chi = (l15 >> 3) * 128;
#pragma unroll
        for (int fn = 0; fn < 16; fn++)
            Ps[base + fn * 256 + chi] = f2bf(v[fn] * rinv);
    }
    VMCNT0;                // V(0) landed
    __syncthreads();       // Ps published

    // ---- phase B: out = P @ v2 -- BARRIER-FREE (V is per-wave private) --
    int it = 0;
    for (int d0 = 0; d0 < Dc; d0 += 128) {
        f32x4 o[8];
#pragma unroll
        for (int qf2 = 0; qf2 < 8; qf2++) o[qf2] = (f32x4){0.f, 0.f, 0.f, 0.f};

        for (int l0 = 0; l0 < LQc; l0 += 32, ++it) {
            if (it < 31) {
                STAGE_V((it + 1) & 1, it + 1);
                VMCNT(1);  // drain V(it) (older, in-order); V(it+1) in flight
            } else {
                VMCNT0;    // last tile: drain everything
            }
            SCHEDB;        // keep the vb ds_read below the fence
            const ushort* v_ = pool + 32768 + (it & 1) * 4096;
            bf16x8 vb = *(const bf16x8*)&v_[wave * 512 + lh * 128 + l15 * 8];
            const int pcol = (l0 >> 3) + lh;     // chunk index of P col
#pragma unroll
            for (int qf2 = 0; qf2 < 8; qf2++) {
                bf16x8 pa = *(const bf16x8*)&Ps[qf2 * 4096 + pcol * 128 + l15 * 8];
                o[qf2] = __builtin_amdgcn_mfma_f32_16x16x32_bf16(pa, vb, o[qf2], 0, 0, 0);
            }
        }
#pragma unroll
        for (int qf2 = 0; qf2 < 8; qf2++)
#pragma unroll
            for (int r = 0; r < 4; r++) {
                const int rowl = qf2 * 16 + lh * 4 + r;
                const int col = d0 + wave * 16 + l15;
                aout[((size_t)n * LQc + q0 + rowl) * Dc + col] = o[qf2][r];
            }
    }
}

// ---------------------------------------------------------------------------
extern "C" void kernel_launch(void* const* d_in, const int* in_sizes, int n_in,
                              void* d_out, int out_size, void* d_ws, size_t ws_size,
                              hipStream_t stream) {
    const float* queries    = (const float*)d_in[0];
    const float* keys       = (const float*)d_in[1];
    const float* values     = (const float*)d_in[2];
    const float* W_q        = (const float*)d_in[3];
    const float* W_k        = (const float*)d_in[4];
    const float* W_v        = (const float*)d_in[5];
    const float* W_o        = (const float*)d_in[6];
    const float* W_len      = (const float*)d_in[7];
    const float* b_len      = (const float*)d_in[8];
    const int*   valid_lens = (const int*)d_in[9];

    char* ws = (char*)d_ws;
    const size_t MB = 1024 * 1024;
    // fold operands ordered for one z-strided launch:
    //   A: [wqT | woBf], B: [wkT | wvT], C: [Eq | G]
    ushort* wqT  = (ushort*)(ws + 128 * MB);
    ushort* woBf = wqT  + 262144;
    ushort* wkT  = woBf + 262144;
    ushort* wvT  = wkT  + 262144;
    ushort* Eq   = wvT  + 262144;                     // Eq[d][c]=sum_e Wq[e,d]Wk[e,c]
    ushort* G    = Eq   + 262144;                     // G[e][c]=sum_d Wo[e,d]Wv[d,c]
    ushort* wl   = G    + 262144;
    ushort* t1k  = wl   + 262144;                     // [32][256][512] bf16 (+ t1v contig)
    ushort* t1v  = t1k  + 4194304;
    ushort* k2   = t1v  + 4194304;
    ushort* v2T  = k2   + 4194304;

    const float alpha_q = 0.044194173824159216f;      // 1/sqrt(512)
    dim3 blk(256);

    // ---- all weight prep in one launch ----------------------------------
    prep_w<<<dim3(16, 16, 5), blk, 0, stream>>>(W_q, W_k, W_v, W_o, W_len,
                                                wqT, wkT, wvT, woBf, wl);
    // folded products Eq and G in ONE z-strided launch
    gemm_bt<1, false, 0><<<dim3(4, 4, 2), blk, 0, stream>>>(
        wqT, wkT, Eq, nullptr, 512, 512, 512, 1.f, 262144, 262144, 262144, 0);

    // ---- fused length-projection from raw fp32 keys/values --------------
    lenproj_f32<<<dim3(4, 2, 64), blk, 0, stream>>>(wl, keys, values, b_len, t1k);

    // k2 = t1k @ Eq-contraction * alpha   (q-proj folded away)
    gemm_bt<1, false, 1><<<dim3(256), blk, 0, stream>>>(
        t1k, Eq, k2, nullptr, 8192, 512, 512, alpha_q, 0, 0, 0, 8);
    // v2T[b][e][q] = (t1v @ G^T)^T          (o-proj folded away)
    gemm_bt<2, false, 1><<<dim3(256), blk, 0, stream>>>(
        t1v, G, v2T, nullptr, 8192, 512, 512, 1.f, 0, 0, 0, 8);

    // ---- attention (raw fp32 queries, reg-Q, 8-wave blocks) -> d_out ----
    attn_mfma<<<dim3(512), dim3(512), 0, stream>>>(queries, k2, v2T, valid_lens,
                                                   (float*)d_out);
}